// Round 7
// baseline (35.869 us; speedup 1.0000x reference)
//
#include <hip/hip_runtime.h>

constexpr int Bdim = 8192;
constexpr int Ddim = 256;
constexpr int NBLK = 2048;                  // 8 blocks/CU, all co-resident
constexpr float MARGIN_F = 0.1f;

typedef int iv4 __attribute__((ext_vector_type(4)));

// d(x,0) = 2*artanh(||x||) = log((1+n)/(1-n)), one wave per row
__global__ __launch_bounds__(256) void k_norm(const float* __restrict__ emb,
                                              float* __restrict__ d) {
    int row  = blockIdx.x * 4 + (threadIdx.x >> 6);
    int lane = threadIdx.x & 63;
    float4 v = ((const float4*)(emb + (size_t)row * Ddim))[lane];
    float s = v.x * v.x + v.y * v.y + v.z * v.z + v.w * v.w;
#pragma unroll
    for (int off = 32; off > 0; off >>= 1) s += __shfl_down(s, off, 64);
    if (lane == 0) {
        float n = fminf(sqrtf(s), 1.0f - 1e-5f);
        d[row] = logf((1.0f + n) / (1.0f - n));
    }
}

// Process one row's suffix j in [r+1, 8192) with the whole 256-thread block.
__device__ __forceinline__ void row_seg(int r, const float* __restrict__ d,
                                        const int* __restrict__ cmp,
                                        int tid, float& s, int& cnt) {
    float dr = d[r];
    int jbeg = r + 1;
    int abeg = (jbeg + 3) & ~3;              // first 16B-aligned column
    int nh   = abeg - jbeg;                  // 0..3 scalar head elements
    if (tid < nh) {
        int j = jbeg + tid;
        int c = cmp[(size_t)r * Bdim + j];
        if (c != 0) {
            float x = fmaf((float)c, d[j] - dr, MARGIN_F);
            s += fmaxf(x, 0.0f); cnt += 1;
        }
    }
    int nq = (Bdim - abeg) >> 2;             // int4 quads in the row
    const iv4*    pv = (const iv4*)(cmp + (size_t)r * Bdim + abeg);
    const float4* dv = (const float4*)(d + abeg);

    int q = tid;
    for (; q + 256 < nq; q += 512) {         // 2-deep: keep 2 loads in flight
        iv4 c0 = pv[q];       float4 dj0 = dv[q];
        iv4 c1 = pv[q + 256]; float4 dj1 = dv[q + 256];
        { bool a = c0.x != 0; float x = fmaf((float)c0.x, dj0.x - dr, MARGIN_F);
          s += a ? fmaxf(x, 0.0f) : 0.0f; cnt += a ? 1 : 0; }
        { bool a = c0.y != 0; float x = fmaf((float)c0.y, dj0.y - dr, MARGIN_F);
          s += a ? fmaxf(x, 0.0f) : 0.0f; cnt += a ? 1 : 0; }
        { bool a = c0.z != 0; float x = fmaf((float)c0.z, dj0.z - dr, MARGIN_F);
          s += a ? fmaxf(x, 0.0f) : 0.0f; cnt += a ? 1 : 0; }
        { bool a = c0.w != 0; float x = fmaf((float)c0.w, dj0.w - dr, MARGIN_F);
          s += a ? fmaxf(x, 0.0f) : 0.0f; cnt += a ? 1 : 0; }
        { bool a = c1.x != 0; float x = fmaf((float)c1.x, dj1.x - dr, MARGIN_F);
          s += a ? fmaxf(x, 0.0f) : 0.0f; cnt += a ? 1 : 0; }
        { bool a = c1.y != 0; float x = fmaf((float)c1.y, dj1.y - dr, MARGIN_F);
          s += a ? fmaxf(x, 0.0f) : 0.0f; cnt += a ? 1 : 0; }
        { bool a = c1.z != 0; float x = fmaf((float)c1.z, dj1.z - dr, MARGIN_F);
          s += a ? fmaxf(x, 0.0f) : 0.0f; cnt += a ? 1 : 0; }
        { bool a = c1.w != 0; float x = fmaf((float)c1.w, dj1.w - dr, MARGIN_F);
          s += a ? fmaxf(x, 0.0f) : 0.0f; cnt += a ? 1 : 0; }
    }
    for (; q < nq; q += 256) {
        iv4 c = pv[q]; float4 dj = dv[q];
        { bool a = c.x != 0; float x = fmaf((float)c.x, dj.x - dr, MARGIN_F);
          s += a ? fmaxf(x, 0.0f) : 0.0f; cnt += a ? 1 : 0; }
        { bool a = c.y != 0; float x = fmaf((float)c.y, dj.y - dr, MARGIN_F);
          s += a ? fmaxf(x, 0.0f) : 0.0f; cnt += a ? 1 : 0; }
        { bool a = c.z != 0; float x = fmaf((float)c.z, dj.z - dr, MARGIN_F);
          s += a ? fmaxf(x, 0.0f) : 0.0f; cnt += a ? 1 : 0; }
        { bool a = c.w != 0; float x = fmaf((float)c.w, dj.w - dr, MARGIN_F);
          s += a ? fmaxf(x, 0.0f) : 0.0f; cnt += a ? 1 : 0; }
    }
}

// Row-paired partition of the strict upper triangle: virtual row v pairs
// row v (len 8191-v) with row 8190-v (len v+1) = exactly 8192 elements.
// Block b handles v=2b and v=2b+1 -> every block 16384 elements (block 2047:
// 12288). Perfect per-block balance, contiguous streaming, no diagonal test.
__global__ __launch_bounds__(256) void k_pairs(const float* __restrict__ d,
                                               const int* __restrict__ cmp,
                                               double* __restrict__ psum,
                                               unsigned int* __restrict__ pcnt) {
    int tid = threadIdx.x;
    float s = 0.0f;
    int cnt = 0;

#pragma unroll
    for (int h = 0; h < 2; ++h) {
        int v  = 2 * blockIdx.x + h;         // 0..4095
        int r0 = v;
        int r1 = 8190 - v;
        row_seg(r0, d, cmp, tid, s, cnt);
        if (r1 != r0) row_seg(r1, d, cmp, tid, s, cnt);
    }

#pragma unroll
    for (int off = 32; off > 0; off >>= 1) {
        s   += __shfl_down(s, off, 64);
        cnt += __shfl_down(cnt, off, 64);
    }
    __shared__ float ws_s[4];
    __shared__ int   ws_c[4];
    int wave = tid >> 6;
    if ((tid & 63) == 0) { ws_s[wave] = s; ws_c[wave] = cnt; }
    __syncthreads();
    if (tid == 0) {
        float st = ws_s[0] + ws_s[1] + ws_s[2] + ws_s[3];
        int   ct = ws_c[0] + ws_c[1] + ws_c[2] + ws_c[3];
        psum[blockIdx.x] = (double)st;
        pcnt[blockIdx.x] = (unsigned int)ct;
    }
}

__global__ __launch_bounds__(256) void k_final(const double* __restrict__ psum,
                                               const unsigned int* __restrict__ pcnt,
                                               float* __restrict__ out) {
    int tid = threadIdx.x;
    double s = 0.0;
    unsigned long long c = 0;
    for (int idx = tid; idx < NBLK; idx += 256) {
        s += psum[idx];
        c += pcnt[idx];
    }
#pragma unroll
    for (int off = 32; off > 0; off >>= 1) {
        s += __shfl_down(s, off, 64);
        c += __shfl_down(c, off, 64);
    }
    __shared__ double sd[4];
    __shared__ unsigned long long sc[4];
    int wave = tid >> 6;
    if ((tid & 63) == 0) { sd[wave] = s; sc[wave] = c; }
    __syncthreads();
    if (tid == 0) {
        double st = sd[0] + sd[1] + sd[2] + sd[3];
        unsigned long long ct = sc[0] + sc[1] + sc[2] + sc[3];
        out[0] = (ct > 0) ? (float)(st / (double)ct) : 0.0f;
    }
}

extern "C" void kernel_launch(void* const* d_in, const int* in_sizes, int n_in,
                              void* d_out, int out_size, void* d_ws, size_t ws_size,
                              hipStream_t stream) {
    const float* emb = (const float*)d_in[0];
    const int*   cmp = (const int*)d_in[1];
    float* out = (float*)d_out;

    char* ws = (char*)d_ws;
    float*        dvec = (float*)ws;                              // 8192 * 4 B
    double*       psum = (double*)(ws + 32768);                   // 2048 * 8 B
    unsigned int* pcnt = (unsigned int*)(ws + 32768 + NBLK * 8);  // 2048 * 4 B

    hipLaunchKernelGGL(k_norm, dim3(Bdim / 4), dim3(256), 0, stream, emb, dvec);
    hipLaunchKernelGGL(k_pairs, dim3(NBLK), dim3(256), 0, stream,
                       dvec, cmp, psum, pcnt);
    hipLaunchKernelGGL(k_final, dim3(1), dim3(256), 0, stream, psum, pcnt, out);
}